// Round 10
// baseline (330.681 us; speedup 1.0000x reference)
//
#include <hip/hip_runtime.h>

#define NN 8192
#define HD 512
#define NL 3
#define CAPQ 48               // ELL capacity per row-quarter (mean nnz/quarter ~17)
#define CAPR (4 * CAPQ)       // 192 u32 per row
#define NWB (273 * NL)
#define NSB 2048              // streaming blocks (x4 waves x4 quarters = 32768 quarters)
#define LN_EPS 1e-5f

typedef _Float16 f16;
typedef _Float16 f16x8 __attribute__((ext_vector_type(8)));
typedef _Float16 f16x4 __attribute__((ext_vector_type(4)));
typedef _Float16 f16x2 __attribute__((ext_vector_type(2)));
typedef float f32x4 __attribute__((ext_vector_type(4)));

__device__ __forceinline__ unsigned short f16_bits(f16 h) {
  union { f16 h; unsigned short u; } x; x.h = h; return x.u;
}
__device__ __forceinline__ f16 bits_f16(unsigned short u) {
  union { unsigned short u; f16 h; } x; x.u = u; return x.h;
}

// ---------------------------------------------------------------------------
// k_prep: blocks [0,NWB) = weight prep; blocks [NWB, NWB+NSB) = adjacency
// streaming.  ONE WAVE OWNS ONE 8KB ROW-QUARTER: all counting/scanning/
// emission is wave-local (shfl only -- no LDS, no __syncthreads), so waves
// never wait on each other, and each wave pipelines 4 quarters with a 2-deep
// register double-buffer: quarter q+1's 8 float4 loads are issued before
// quarter q's scan/emit tail runs.  This keeps the per-wave load train deep
// and the load-issue duty cycle high -- the one axis unchanged across the
// three prior (all ~1.7 TB/s) geometries.
// Emits segment-local ELL (u32 = f16(w)<<16 | col) at ell[(r*4+seg)*CAPQ],
// self-loop w=1 appended by owning quarter (seg == r>>11; diag of A is always
// 0), w=0 pad to multiple of 8, count in nnz8q[r*4+seg], weight-sum in
// psum[r*4+seg].
__global__ __launch_bounds__(256) void k_prep(const float* __restrict__ A,
                                              const float* __restrict__ convw,
                                              const float* __restrict__ mlpw,
                                              const float* __restrict__ convb,
                                              const float* __restrict__ mlpb,
                                              const float* __restrict__ lw,
                                              unsigned* __restrict__ ell,
                                              int* __restrict__ nnz8q,
                                              float* __restrict__ psum,
                                              f16* __restrict__ WlT,
                                              float* __restrict__ bl,
                                              f16* __restrict__ lwT) {
  const int b = blockIdx.x;
  const int t = threadIdx.x;

  if (b < NWB) {                       // ---------------- weight-prep blocks
    const int l = b / 273;
    const int bx = b % 273;
    if (bx < 256) {
      const int m0 = bx * 2;
      const float* Wc = convw + (size_t)l * HD * HD;
      const float* Wm = mlpw + (size_t)l * HD * HD;
      f16* o = WlT + (size_t)l * HD * HD;
      float a00 = 0.f, a01 = 0.f, a10 = 0.f, a11 = 0.f;
      const float* wc0 = Wc + (size_t)m0 * HD;
      const float* wc1 = Wc + (size_t)(m0 + 1) * HD;
      for (int k = 0; k < HD; k++) {
        const float w0 = Wm[(size_t)k * HD + t];
        const float w1 = Wm[(size_t)k * HD + t + 256];
        const float c0 = wc0[k];
        const float c1 = wc1[k];
        a00 = fmaf(c0, w0, a00);
        a01 = fmaf(c0, w1, a01);
        a10 = fmaf(c1, w0, a10);
        a11 = fmaf(c1, w1, a11);
      }
      o[(size_t)t * HD + m0] = (f16)a00;
      o[(size_t)(t + 256) * HD + m0] = (f16)a01;
      o[(size_t)t * HD + m0 + 1] = (f16)a10;
      o[(size_t)(t + 256) * HD + m0 + 1] = (f16)a11;
    } else if (bx == 256) {
      const float* Wm = mlpw + (size_t)l * HD * HD;
      float acc0 = mlpb[l * HD + t];
      float acc1 = mlpb[l * HD + t + 256];
      for (int k = 0; k < HD; k++) {
        const float cb = convb[l * HD + k];
        acc0 = fmaf(cb, Wm[(size_t)k * HD + t], acc0);
        acc1 = fmaf(cb, Wm[(size_t)k * HD + t + 256], acc1);
      }
      bl[l * HD + t] = acc0;
      bl[l * HD + t + 256] = acc1;
    } else if (l == 0) {
      const int base = (bx - 257) * 16384;   // 16 blocks cover 512*512
      #pragma unroll 4
      for (int j = 0; j < 64; j++) {
        const int idx = base + j * 256 + t;
        const int k = idx >> 9, n = idx & 511;
        lwT[(size_t)n * HD + k] = (f16)lw[idx];
      }
    }
    return;
  }

  // --------------------------------------------- streaming waves (no LDS)
  const int lane = t & 63;
  const int wid = (b - NWB) * 4 + (t >> 6);   // 0..8191

  auto LOADQ = [&](int qidx, float4* v) {
    const int r = qidx >> 2, seg = qidx & 3;
    const float4* aseg = (const float4*)(A + (size_t)r * NN + seg * 2048);
    #pragma unroll
    for (int i = 0; i < 8; i++) v[i] = aseg[lane + i * 64];
  };

  auto PROC = [&](int qidx, const float4* v) {
    const int r = qidx >> 2, seg = qidx & 3;
    unsigned* er = ell + (size_t)qidx * CAPQ;
    int c = 0;
    float s = 0.f;
    #pragma unroll
    for (int i = 0; i < 8; i++) {
      c += (v[i].x > 0.f) + (v[i].y > 0.f) + (v[i].z > 0.f) + (v[i].w > 0.f);
      s += v[i].x + v[i].y + v[i].z + v[i].w;     // entries are >= 0
    }
    int inc = c;
    #pragma unroll
    for (int d = 1; d < 64; d <<= 1) {
      int vv = __shfl_up(inc, d);
      if (lane >= d) inc += vv;
    }
    float ss = s;
    #pragma unroll
    for (int m = 1; m < 64; m <<= 1) ss += __shfl_xor(ss, m);
    int o = inc - c;                              // exclusive scan
    #pragma unroll
    for (int i = 0; i < 8; i++) {
      const int cb = seg * 2048 + (lane + i * 64) * 4;
      float vals[4] = {v[i].x, v[i].y, v[i].z, v[i].w};
      #pragma unroll
      for (int q = 0; q < 4; q++) {
        if (vals[q] > 0.f) {
          if (o < CAPQ) er[o] = ((unsigned)f16_bits((f16)vals[q]) << 16) | (unsigned)(cb + q);
          o++;
        }
      }
    }
    int ne = __shfl(inc, 63);                     // wave total
    if (lane == 0) {
      if (ne > CAPQ) ne = CAPQ;
      const bool own = (seg == (r >> 11));        // self-loop lives here
      if (own && ne < CAPQ) { er[ne] = (0x3C00u << 16) | (unsigned)r; ne++; }
      const int n8 = (ne + 7) & ~7;
      for (int k = ne; k < n8; k++) er[k] = (unsigned)r;   // w = +0.0 pad
      nnz8q[qidx] = n8;
      psum[qidx] = ss;
    }
  };

  float4 va[8], vb[8];
  LOADQ(wid, va);                                  // quarter 0
  LOADQ(wid + 8192, vb);                           // quarter 1 (in flight)
  PROC(wid, va);
  LOADQ(wid + 16384, va);                          // quarter 2
  PROC(wid + 8192, vb);
  LOADQ(wid + 24576, vb);                          // quarter 3
  PROC(wid + 16384, va);
  PROC(wid + 24576, vb);
}

// ---------------------------------------------------------------------------
// k_deg: reduce the 4 segment sums -> dinv = (rowsum+1)^-1/2; fused x-scale
// xs[r] = x0[r] * dinv[r] (f16).  2048 blocks x 4 waves, one row per wave.
__global__ __launch_bounds__(256) void k_deg(const float* __restrict__ psum,
                                             const float* __restrict__ x0,
                                             float* __restrict__ dinv,
                                             f16* __restrict__ xs) {
  const int r = blockIdx.x * 4 + (threadIdx.x >> 6);
  const int lane = threadIdx.x & 63;
  const float4 ps = *(const float4*)(psum + (size_t)r * 4);   // wave-uniform
  const float di = rsqrtf(ps.x + ps.y + ps.z + ps.w + 1.f);
  if (lane == 0) dinv[r] = di;
  const float4* xr = (const float4*)(x0 + (size_t)r * HD);
  const float4 a = xr[lane * 2];
  const float4 bq = xr[lane * 2 + 1];
  f16x8 o = {(f16)(a.x * di), (f16)(a.y * di), (f16)(a.z * di), (f16)(a.w * di),
             (f16)(bq.x * di), (f16)(bq.y * di), (f16)(bq.z * di), (f16)(bq.w * di)};
  *(f16x8*)(xs + (size_t)r * HD + lane * 8) = o;
}

// ---------------------------------------------------------------------------
// Column-chunked SpMM over segmented ELL: y[r] = dinv[r] * sum w_e*xs[col_e].
// chunk = bid&3 (co-resident blocks cover all four 256B column windows).
// 4 waves/block, one row each; edge words via uniform s_loads; per edge per
// lane: one f16x2 gather + 2 fma.
__global__ __launch_bounds__(256) void k_spmm(const unsigned* __restrict__ ell,
                                              const int* __restrict__ nnz8q,
                                              const float* __restrict__ dinv,
                                              const f16* __restrict__ xs,
                                              f16* __restrict__ y) {
  const int bid = blockIdx.x;              // 0..8191
  const int chunk = bid & 3;
  const int rb = bid >> 2;
  const int r = __builtin_amdgcn_readfirstlane(rb * 4 + (threadIdx.x >> 6));
  const int lane = threadIdx.x & 63;
  const int c0 = chunk * 128 + lane * 2;
  const unsigned* erow = ell + (size_t)r * CAPR;
  const int4 nn = *(const int4*)(nnz8q + (size_t)r * 4);
  const int ne8s[4] = {nn.x >> 3, nn.y >> 3, nn.z >> 3, nn.w >> 3};
  const f16* xc = xs + c0;
  float a0 = 0.f, a1 = 0.f;
  #pragma unroll
  for (int seg = 0; seg < 4; seg++) {
    const uint4* er = (const uint4*)(erow + seg * CAPQ);
    const int ne8 = ne8s[seg];
    for (int e8 = 0; e8 < ne8; e8++) {
      const uint4 ea = er[e8 * 2];
      const uint4 eb = er[e8 * 2 + 1];
      unsigned wv[8] = {ea.x, ea.y, ea.z, ea.w, eb.x, eb.y, eb.z, eb.w};
      f16x2 xv[8];
      #pragma unroll
      for (int q = 0; q < 8; q++)
        xv[q] = *(const f16x2*)(xc + (size_t)(wv[q] & 0xFFFFu) * HD);
      #pragma unroll
      for (int q = 0; q < 8; q++) {
        const float fw = (float)bits_f16((unsigned short)(wv[q] >> 16));
        a0 = fmaf(fw, (float)xv[q][0], a0);
        a1 = fmaf(fw, (float)xv[q][1], a1);
      }
    }
  }
  const float s = dinv[r];
  f16x2 o = {(f16)(a0 * s), (f16)(a1 * s)};
  *(f16x2*)(y + (size_t)r * HD + c0) = o;
}

// ---------------------------------------------------------------------------
// Fused GEMM + bias + LayerNorm + ReLU + optional dinv scale, f16 out.
// M=32 x N=512 per block (256 blocks), 512 threads = 8 waves (2 rowgroups x
// 4 colgroups); per-CU W streaming = 512 KB.
__global__ __launch_bounds__(512) void k_gemm_ln(const f16* __restrict__ y,
                                                 const f16* __restrict__ WT,
                                                 const float* __restrict__ bias,
                                                 const float* __restrict__ g,
                                                 const float* __restrict__ bb,
                                                 const float* __restrict__ dscale,
                                                 f16* __restrict__ outp) {
  __shared__ float red[32][4][2];
  const int t = threadIdx.x;
  const int lane = t & 63;
  const int w = t >> 6;
  const int wm = w >> 2;          // 0..1 rowgroup
  const int wn = w & 3;           // 0..3 colgroup
  const int m0 = blockIdx.x * 32;
  const int rl = lane & 15, kg = (lane >> 4) * 8;
  const f16* aP = y + (size_t)(m0 + wm * 16 + rl) * HD + kg;
  const f16* bP = WT + (size_t)(wn * 128 + rl) * HD + kg;

  f32x4 acc[8];
  #pragma unroll
  for (int j = 0; j < 8; j++) { f32x4 z = {0.f, 0.f, 0.f, 0.f}; acc[j] = z; }

  #pragma unroll 2
  for (int ks = 0; ks < HD; ks += 32) {
    const f16x8 af = *(const f16x8*)(aP + ks);
    #pragma unroll
    for (int j = 0; j < 8; j++) {
      const f16x8 bf = *(const f16x8*)(bP + (size_t)j * 16 * HD + ks);
      acc[j] = __builtin_amdgcn_mfma_f32_16x16x32_f16(af, bf, acc[j], 0, 0, 0);
    }
  }

  const int cg = lane >> 4, cl = lane & 15;
  float av[8][4];
  #pragma unroll
  for (int j = 0; j < 8; j++) {
    const float bv = bias[wn * 128 + j * 16 + cl];
    #pragma unroll
    for (int r = 0; r < 4; r++) av[j][r] = acc[j][r] + bv;
  }
  #pragma unroll
  for (int r = 0; r < 4; r++) {
    float s = 0.f, sq = 0.f;
    #pragma unroll
    for (int j = 0; j < 8; j++) { s += av[j][r]; sq += av[j][r] * av[j][r]; }
    #pragma unroll
    for (int m = 1; m < 16; m <<= 1) { s += __shfl_xor(s, m); sq += __shfl_xor(sq, m); }
    if (cl == 0) {
      red[wm * 16 + cg * 4 + r][wn][0] = s;
      red[wm * 16 + cg * 4 + r][wn][1] = sq;
    }
  }
  __syncthreads();
  #pragma unroll
  for (int r = 0; r < 4; r++) {
    const int rb = wm * 16 + cg * 4 + r;
    float s = 0.f, sq = 0.f;
    #pragma unroll
    for (int q = 0; q < 4; q++) { s += red[rb][q][0]; sq += red[rb][q][1]; }
    const float mu = s * (1.f / HD);
    const float rs = rsqrtf(sq * (1.f / HD) - mu * mu + LN_EPS);
    const int row = m0 + rb;
    const float dsc = dscale ? dscale[row] : 1.f;
    #pragma unroll
    for (int j = 0; j < 8; j++) {
      const int col = wn * 128 + j * 16 + cl;
      const float val = fmaxf((av[j][r] - mu) * rs * g[col] + bb[col], 0.f) * dsc;
      outp[(size_t)row * HD + col] = (f16)val;
    }
  }
}

// ---------------------------------------------------------------------------
// Direct-from-L2 MFMA GEMM (final linear): C[M,512] = A[M,512] @ BT^T + bias.
__global__ __launch_bounds__(256) void k_gemm_direct(const f16* __restrict__ A,
                                                     const f16* __restrict__ BT,
                                                     float* __restrict__ C,
                                                     const float* __restrict__ bias) {
  const int t = threadIdx.x;
  const int lane = t & 63;
  const int wave = t >> 6;
  const int wm = wave >> 1, wn = wave & 1;
  const int m0 = blockIdx.x * 128, n0 = blockIdx.y * 128;
  const int rl = lane & 15, kg = (lane >> 4) * 8;

  const f16* aP[4];
  const f16* bP[4];
  #pragma unroll
  for (int i = 0; i < 4; i++)
    aP[i] = A + (size_t)(m0 + wm * 64 + i * 16 + rl) * HD + kg;
  #pragma unroll
  for (int j = 0; j < 4; j++)
    bP[j] = BT + (size_t)(n0 + wn * 64 + j * 16 + rl) * HD + kg;

  f32x4 acc[4][4];
  #pragma unroll
  for (int i = 0; i < 4; i++)
    #pragma unroll
    for (int j = 0; j < 4; j++) {
      f32x4 z = {0.f, 0.f, 0.f, 0.f};
      acc[i][j] = z;
    }

  #pragma unroll 4
  for (int ks = 0; ks < HD; ks += 32) {
    f16x8 af[4], bf[4];
    #pragma unroll
    for (int i = 0; i < 4; i++) af[i] = *(const f16x8*)(aP[i] + ks);
    #pragma unroll
    for (int j = 0; j < 4; j++) bf[j] = *(const f16x8*)(bP[j] + ks);
    #pragma unroll
    for (int i = 0; i < 4; i++)
      #pragma unroll
      for (int j = 0; j < 4; j++)
        acc[i][j] = __builtin_amdgcn_mfma_f32_16x16x32_f16(af[i], bf[j], acc[i][j], 0, 0, 0);
  }

  const int cg = lane >> 4, cl = lane & 15;
  #pragma unroll
  for (int i = 0; i < 4; i++) {
    #pragma unroll
    for (int j = 0; j < 4; j++) {
      const int col = n0 + wn * 64 + j * 16 + cl;
      const float bv = bias ? bias[col] : 0.f;
      #pragma unroll
      for (int rr = 0; rr < 4; rr++) {
        const int row = m0 + wm * 64 + i * 16 + cg * 4 + rr;
        C[(size_t)row * HD + col] = acc[i][j][rr] + bv;
      }
    }
  }
}

// ---------------------------------------------------------------------------
extern "C" void kernel_launch(void* const* d_in, const int* in_sizes, int n_in,
                              void* d_out, int out_size, void* d_ws, size_t ws_size,
                              hipStream_t stream) {
  const float* node_feat = (const float*)d_in[0];
  const float* adj       = (const float*)d_in[1];
  const float* conv_w    = (const float*)d_in[2];
  const float* conv_b    = (const float*)d_in[3];
  const float* mlp_w     = (const float*)d_in[4];
  const float* mlp_b     = (const float*)d_in[5];
  const float* ln_g      = (const float*)d_in[6];
  const float* ln_b      = (const float*)d_in[7];
  const float* lin_w     = (const float*)d_in[8];
  const float* lin_b     = (const float*)d_in[9];
  float* out = (float*)d_out;

  // workspace carve (~33 MB)
  char* p = (char*)d_ws;
  unsigned* ell = (unsigned*)p; p += (size_t)NN * CAPR * 4;  // 6 MB
  int* nnz8q = (int*)p;  p += (size_t)NN * 4 * 4;            // 128 KB
  float* psum = (float*)p; p += (size_t)NN * 4 * 4;          // 128 KB
  float* dinv = (float*)p; p += (size_t)NN * 4;
  f16* xsA   = (f16*)p;   p += (size_t)NN * HD * 2;          // 8 MB
  f16* xsB   = (f16*)p;   p += (size_t)NN * HD * 2;          // 8 MB
  f16* ybuf  = (f16*)p;   p += (size_t)NN * HD * 2;          // 8 MB
  f16* WlT   = (f16*)p;   p += (size_t)NL * HD * HD * 2;
  f16* lwT   = (f16*)p;   p += (size_t)HD * HD * 2;
  float* bl  = (float*)p; p += (size_t)NL * HD * 4;

  k_prep<<<NWB + NSB, 256, 0, stream>>>(adj, conv_w, mlp_w, conv_b, mlp_b,
                                        lin_w, ell, nnz8q, psum, WlT, bl, lwT);
  k_deg<<<NN / 4, 256, 0, stream>>>(psum, node_feat, dinv, xsA);

  f16* xcur = xsA;
  for (int l = 0; l < NL; l++) {
    k_spmm<<<NN, 256, 0, stream>>>(ell, nnz8q, dinv, xcur, ybuf);
    f16* nxt = (xcur == xsA) ? xsB : xsA;
    k_gemm_ln<<<NN / 32, 512, 0, stream>>>(ybuf, WlT + (size_t)l * HD * HD,
                                           bl + l * HD, ln_g + l * HD, ln_b + l * HD,
                                           (l < 2) ? dinv : nullptr, nxt);
    xcur = nxt;
  }
  k_gemm_direct<<<dim3(64, 4), 256, 0, stream>>>(xcur, lwT, out, lin_b);
}